// Round 4
// baseline (142.329 us; speedup 1.0000x reference)
//
#include <hip/hip_runtime.h>

#define BATCH 32
#define H 512
#define W 512
#define PADR 4
#define WIN 9
#define SEG 8                       // output rows per block (8 -> 2048 blocks)
#define COLS 4                      // output columns per thread
#define NT 128                      // threads per block (covers W=512)
#define NSTEP (SEG + WIN - 1)       // 16 row-steps, fully unrolled
// final scalar = sum over pixels of ((1-cc1)+(1-cc2)) * 0.5 / (B*H*W)
#define SCALE (0.5f / 8388608.0f)

typedef float v4f __attribute__((ext_vector_type(4)));

// Vertical-first NCC, round 4:
//  - round-3 structure unchanged (raw-pixel ring + vertical running sums +
//    single-buffered prefix-pack LDS exchange, VGPR=124, LDS=16.6KB)
//  - SEG 16 -> 8: grid 1024 -> 2048 blocks = 8 blocks/CU co-resident
//    (rounds 2-3 were GRID-capped at 4 blocks/CU / 25% occupancy ceiling;
//    LDS 16.9KB x 8 = 135KB < 160KB, VGPR 124 <= 128 -> 4 waves/SIMD, so
//    the round-3 headroom is now actually consumed).
//    Cost: vertical halo redundancy 1.5x -> 2.0x (+33% loads/vert-VALU),
//    paid against a VALU pipe that was 70% idle.
__global__ __launch_bounds__(NT, 1) void ncc_loss_kernel(
    const float* __restrict__ g1, const float* __restrict__ g2,
    const float* __restrict__ gf, float* __restrict__ out)
{
    const int t  = threadIdx.x;              // 0..127
    const int x0 = t * COLS;                 // 0,4,...,508
    const int y0 = blockIdx.y * SEG;
    const int b  = blockIdx.z;
    const size_t base = (size_t)b * (size_t)(H * W);
    const int voff = x0 * 4;                 // always in-bounds horizontally

    // Prefix-pack exchange row: [quantity][4 guard | 512 | 4 guard] floats.
    // Single-buffered: write-protect barrier at top of each emit.
    __shared__ __align__(16) float Vl[8][520];          // 16,640 B
    if (t < 64) {                            // zero the 8q x 8 guard entries
        const int gp  = t & 7;               // 0..7
        const int q   = t >> 3;              // 0..7
        const int idx = (gp < 4) ? gp : (512 + gp);     // 0..3 / 516..519
        Vl[q][idx] = 0.0f;                   // ordered before reads by emit barrier
    }

    // Double-buffered prefetch: [parity][image], 4 pixels each.
    v4f buf[2][3];
    auto load_row = [&](int step, int par) {
        const int yr  = y0 - PADR + step;
        const int rec = ((unsigned)yr < (unsigned)H) ? (W * 4) : 0; // OOB row -> 0
        const int yc  = yr < 0 ? 0 : (yr >= H ? H - 1 : yr);        // safe base
        const size_t roff = base + (size_t)yc * W;                  // block-uniform
        __amdgpu_buffer_rsrc_t r1 = __builtin_amdgcn_make_buffer_rsrc(
            (void*)(g1 + roff), (short)0, rec, 0x00020000);
        __amdgpu_buffer_rsrc_t r2 = __builtin_amdgcn_make_buffer_rsrc(
            (void*)(g2 + roff), (short)0, rec, 0x00020000);
        __amdgpu_buffer_rsrc_t rf = __builtin_amdgcn_make_buffer_rsrc(
            (void*)(gf + roff), (short)0, rec, 0x00020000);
        buf[par][0] = __builtin_bit_cast(v4f,
            __builtin_amdgcn_raw_buffer_load_b128(r1, voff, 0, 0));
        buf[par][1] = __builtin_bit_cast(v4f,
            __builtin_amdgcn_raw_buffer_load_b128(r2, voff, 0, 0));
        buf[par][2] = __builtin_bit_cast(v4f,
            __builtin_amdgcn_raw_buffer_load_b128(rf, voff, 0, 0));
    };

    // Raw-pixel vertical ring (all indices compile-time after full unroll).
    float ring[3][WIN][COLS];
#pragma unroll
    for (int im = 0; im < 3; ++im)
#pragma unroll
        for (int i = 0; i < WIN; ++i)
#pragma unroll
            for (int c = 0; c < COLS; ++c) ring[im][i][c] = 0.f;

    // Vertical running box-sums: q = {A, C, F, AA, CC, FF, AF, CF}.
    float V[8][COLS];
#pragma unroll
    for (int q = 0; q < 8; ++q)
#pragma unroll
        for (int c = 0; c < COLS; ++c) V[q][c] = 0.f;

    float lsum = 0.f;
    const float inv_n = 1.0f / 81.0f;

    load_row(0, 0);                          // prologue prefetch

#pragma unroll
    for (int s = 0; s < NSTEP; ++s) {
        if (s + 1 < NSTEP) load_row(s + 1, (s + 1) & 1);   // compile-time guard

        const v4f A = buf[s & 1][0];
        const v4f C = buf[s & 1][1];
        const v4f F = buf[s & 1][2];
        const int ph = s % WIN;              // compile-time

        // vertical sliding update: V += new - old (products folded as fma)
#pragma unroll
        for (int c = 0; c < COLS; ++c) {
            const float n1 = A[c], n2 = C[c], nf = F[c];
            const float o1 = ring[0][ph][c], o2 = ring[1][ph][c],
                        of = ring[2][ph][c];
            V[0][c] += n1 - o1;
            V[1][c] += n2 - o2;
            V[2][c] += nf - of;
            V[3][c] = fmaf(n1, n1, fmaf(-o1, o1, V[3][c]));
            V[4][c] = fmaf(n2, n2, fmaf(-o2, o2, V[4][c]));
            V[5][c] = fmaf(nf, nf, fmaf(-of, of, V[5][c]));
            V[6][c] = fmaf(n1, nf, fmaf(-o1, of, V[6][c]));
            V[7][c] = fmaf(n2, nf, fmaf(-o2, of, V[7][c]));
            ring[0][ph][c] = n1; ring[1][ph][c] = n2; ring[2][ph][c] = nf;
        }

        if (s >= WIN - 1) {                  // emit output row y0 + s - 8
            // single-buffer write-protect: previous emit's reads must finish
            if (s > WIN - 1) __syncthreads();

            // publish prefix packs (p1, p2, p3, T) per quantity
            float Tq[8];
#pragma unroll
            for (int q = 0; q < 8; ++q) {
                const float p1 = V[q][0];
                const float p2 = p1 + V[q][1];
                const float p3 = p2 + V[q][2];
                const float tt = p3 + V[q][3];
                Tq[q] = tt;
                v4f v; v.x = p1; v.y = p2; v.z = p3; v.w = tt;
                *(v4f*)&Vl[q][4 + 4 * t] = v;
            }
            __syncthreads();

            // window sums: S[j] = Lsuf(4-j) + T_own + Rpre(j+1)
            float S[8][COLS];
#pragma unroll
            for (int q = 0; q < 8; ++q) {
                const v4f Lp = *(const v4f*)&Vl[q][4 * t];       // left pack
                const v4f Rp = *(const v4f*)&Vl[q][4 * t + 8];   // right pack
                const float lT  = Lp.w;
                const float TT  = Tq[q];
                S[q][0] = (lT         + TT) + Rp.x;
                S[q][1] = ((lT - Lp.x) + TT) + Rp.y;
                S[q][2] = ((lT - Lp.y) + TT) + Rp.z;
                S[q][3] = ((lT - Lp.z) + TT) + Rp.w;
            }

            // NCC epilogue per column
#pragma unroll
            for (int c = 0; c < COLS; ++c) {
                const float sA = S[0][c], sC = S[1][c], sF = S[2][c];
                const float u1 = sA * inv_n;
                const float u2 = sC * inv_n;
                const float uf = sF * inv_n;
                const float cross1 = fmaf(-sA, uf, S[6][c]);
                const float var1   = fmaf(-sA, u1, S[3][c]);
                const float varf   = fmaf(-sF, uf, S[5][c]);
                const float cross2 = fmaf(-sC, uf, S[7][c]);
                const float var2   = fmaf(-sC, u2, S[4][c]);
                const float d1 = fmaf(var1, varf, 1e-5f);
                const float d2 = fmaf(var2, varf, 1e-5f);
                // cc1 + cc2 = (cross1^2*d2 + cross2^2*d1)/(d1*d2): single rcp
                const float inv = __builtin_amdgcn_rcpf(d1 * d2);
                float num = cross1 * cross1 * d2;
                num = fmaf(cross2 * cross2, d1, num);
                lsum += fmaf(-num, inv, 2.0f);   // (1-cc1)+(1-cc2)
            }
        }
    }

    // block reduction: wave shuffle -> LDS -> one atomic per block
#pragma unroll
    for (int offd = 32; offd > 0; offd >>= 1)
        lsum += __shfl_down(lsum, offd);
    __shared__ float wsum[2];
    const int lane = t & 63;
    const int wid  = t >> 6;
    if (lane == 0) wsum[wid] = lsum;
    __syncthreads();
    if (t == 0) atomicAdd(out, (wsum[0] + wsum[1]) * SCALE);
}

extern "C" void kernel_launch(void* const* d_in, const int* in_sizes, int n_in,
                              void* d_out, int out_size, void* d_ws, size_t ws_size,
                              hipStream_t stream) {
    const float* img1 = (const float*)d_in[0];
    const float* img2 = (const float*)d_in[1];
    const float* fimg = (const float*)d_in[2];
    float* out = (float*)d_out;

    hipMemsetAsync(out, 0, sizeof(float), stream);  // d_out re-poisoned each call

    dim3 grid(1, H / SEG, BATCH);        // (1, 64, 32) = 2048 blocks
    ncc_loss_kernel<<<grid, dim3(NT), 0, stream>>>(img1, img2, fimg, out);
}

// Round 5
// 127.261 us; speedup vs baseline: 1.1184x; 1.1184x over previous
//
#include <hip/hip_runtime.h>

#define BATCH 32
#define H 512
#define W 512
#define PADR 4
#define WIN 9
#define SEG 16                      // output rows per block
#define COLS 2                      // output columns per thread (was 4)
#define NT 256                      // threads per block (covers W=512)
#define NSTEP (SEG + WIN - 1)       // 24 row-steps, fully unrolled
// final scalar = sum over pixels of ((1-cc1)+(1-cc2)) * 0.5 / (B*H*W)
#define SCALE (0.5f / 8388608.0f)

typedef float v2f __attribute__((ext_vector_type(2)));
typedef float v4f __attribute__((ext_vector_type(4)));

// Round 5: register-occupancy attack.
// Rounds 1-4 fit: co-residency capped at 4 blocks/CU (2 waves/SIMD) in ALL
// configs -> true unified reg usage ~210-230 (ring 108 dominates; reported
// VGPR_Count hides the AGPR half of the unified file).  COLS 4 -> 2 halves
// the ring (54) -> true ~140-150; __launch_bounds__(NT,3) enforces <=170
// (>=3 waves/SIMD).  Exchange packs are (p1,T) per q, q-paired into v4f.
__global__ __launch_bounds__(NT, 3) void ncc_loss_kernel(
    const float* __restrict__ g1, const float* __restrict__ g2,
    const float* __restrict__ gf, float* __restrict__ out)
{
    const int t  = threadIdx.x;              // 0..255
    const int x0 = t * COLS;                 // 0,2,...,510
    const int y0 = blockIdx.y * SEG;
    const int b  = blockIdx.z;
    const size_t base = (size_t)b * (size_t)(H * W);
    const int voff = x0 * 4;                 // always in-bounds horizontally

    // Pack exchange: [q-pair][2 guard | 256 packs | 2 guard] of v4f
    // pack(thread) = (p1_qa, T_qa, p1_qb, T_qb); 16,640 B total.
    __shared__ v4f Vl[4][260];
    if (t < 16) {                            // zero the 4qp x 4 guard slots
        const int qp  = t >> 2;
        const int g   = t & 3;
        const int idx = (g < 2) ? g : (256 + g);   // 0,1,258,259
        Vl[qp][idx] = v4f{0.f, 0.f, 0.f, 0.f};     // ordered by emit barrier
    }

    // Double-buffered prefetch: [parity][image], 2 pixels each (b64).
    v2f buf[2][3];
    auto load_row = [&](int step, int par) {
        const int yr  = y0 - PADR + step;
        const int rec = ((unsigned)yr < (unsigned)H) ? (W * 4) : 0; // OOB row -> 0
        const int yc  = yr < 0 ? 0 : (yr >= H ? H - 1 : yr);        // safe base
        const size_t roff = base + (size_t)yc * W;                  // block-uniform
        __amdgpu_buffer_rsrc_t r1 = __builtin_amdgcn_make_buffer_rsrc(
            (void*)(g1 + roff), (short)0, rec, 0x00020000);
        __amdgpu_buffer_rsrc_t r2 = __builtin_amdgcn_make_buffer_rsrc(
            (void*)(g2 + roff), (short)0, rec, 0x00020000);
        __amdgpu_buffer_rsrc_t rf = __builtin_amdgcn_make_buffer_rsrc(
            (void*)(gf + roff), (short)0, rec, 0x00020000);
        buf[par][0] = __builtin_bit_cast(v2f,
            __builtin_amdgcn_raw_buffer_load_b64(r1, voff, 0, 0));
        buf[par][1] = __builtin_bit_cast(v2f,
            __builtin_amdgcn_raw_buffer_load_b64(r2, voff, 0, 0));
        buf[par][2] = __builtin_bit_cast(v2f,
            __builtin_amdgcn_raw_buffer_load_b64(rf, voff, 0, 0));
    };

    // Raw-pixel vertical ring (compile-time indices after full unroll).
    float ring[3][WIN][COLS];
#pragma unroll
    for (int im = 0; im < 3; ++im)
#pragma unroll
        for (int i = 0; i < WIN; ++i)
#pragma unroll
            for (int c = 0; c < COLS; ++c) ring[im][i][c] = 0.f;

    // Vertical running box-sums: q = {A, C, F, AA, CC, FF, AF, CF}.
    float V[8][COLS];
#pragma unroll
    for (int q = 0; q < 8; ++q)
#pragma unroll
        for (int c = 0; c < COLS; ++c) V[q][c] = 0.f;

    float lsum = 0.f;
    const float inv_n = 1.0f / 81.0f;

    load_row(0, 0);                          // prologue prefetch

#pragma unroll
    for (int s = 0; s < NSTEP; ++s) {
        if (s + 1 < NSTEP) load_row(s + 1, (s + 1) & 1);   // compile-time guard

        const v2f A = buf[s & 1][0];
        const v2f C = buf[s & 1][1];
        const v2f F = buf[s & 1][2];
        const int ph = s % WIN;              // compile-time

        // vertical sliding update: V += new - old (products folded as fma)
#pragma unroll
        for (int c = 0; c < COLS; ++c) {
            const float n1 = A[c], n2 = C[c], nf = F[c];
            const float o1 = ring[0][ph][c], o2 = ring[1][ph][c],
                        of = ring[2][ph][c];
            V[0][c] += n1 - o1;
            V[1][c] += n2 - o2;
            V[2][c] += nf - of;
            V[3][c] = fmaf(n1, n1, fmaf(-o1, o1, V[3][c]));
            V[4][c] = fmaf(n2, n2, fmaf(-o2, o2, V[4][c]));
            V[5][c] = fmaf(nf, nf, fmaf(-of, of, V[5][c]));
            V[6][c] = fmaf(n1, nf, fmaf(-o1, of, V[6][c]));
            V[7][c] = fmaf(n2, nf, fmaf(-o2, of, V[7][c]));
            ring[0][ph][c] = n1; ring[1][ph][c] = n2; ring[2][ph][c] = nf;
        }

        if (s >= WIN - 1) {                  // emit output row y0 + s - 8
            // single-buffer write-protect: previous emit's reads must finish
            if (s > WIN - 1) __syncthreads();

            // publish q-paired packs (p1_qa, T_qa, p1_qb, T_qb)
            v4f pk[4];
#pragma unroll
            for (int qp = 0; qp < 4; ++qp) {
                const int qa = 2 * qp, qb = 2 * qp + 1;
                v4f v;
                v.x = V[qa][0]; v.y = V[qa][0] + V[qa][1];
                v.z = V[qb][0]; v.w = V[qb][0] + V[qb][1];
                Vl[qp][2 + t] = v;
                pk[qp] = v;                  // own pack stays in registers
            }
            __syncthreads();

            // window sums for 2 cols per q from neighbor packs:
            // col x0  : T(t-2)+T(t-1)+T(t)+T(t+1)+p1(t+2)
            // col x0+1: (T(t-2)-p1(t-2))+T(t-1)+T(t)+T(t+1)+T(t+2)
            float S[8][COLS];
#pragma unroll
            for (int qp = 0; qp < 4; ++qp) {
                const v4f L0 = Vl[qp][t];        // thread t-2
                const v4f L1 = Vl[qp][t + 1];    // thread t-1
                const v4f R1 = Vl[qp][t + 3];    // thread t+1
                const v4f R2 = Vl[qp][t + 4];    // thread t+2
                {
                    const int q = 2 * qp;        // qa: .x=p1, .y=T
                    const float com = L1.y + pk[qp].y + R1.y;
                    S[q][0] = (com + L0.y) + R2.x;
                    S[q][1] = (com + (L0.y - L0.x)) + R2.y;
                }
                {
                    const int q = 2 * qp + 1;    // qb: .z=p1, .w=T
                    const float com = L1.w + pk[qp].w + R1.w;
                    S[q][0] = (com + L0.w) + R2.z;
                    S[q][1] = (com + (L0.w - L0.z)) + R2.w;
                }
            }

            // NCC epilogue per column
#pragma unroll
            for (int c = 0; c < COLS; ++c) {
                const float sA = S[0][c], sC = S[1][c], sF = S[2][c];
                const float u1 = sA * inv_n;
                const float u2 = sC * inv_n;
                const float uf = sF * inv_n;
                const float cross1 = fmaf(-sA, uf, S[6][c]);
                const float var1   = fmaf(-sA, u1, S[3][c]);
                const float varf   = fmaf(-sF, uf, S[5][c]);
                const float cross2 = fmaf(-sC, uf, S[7][c]);
                const float var2   = fmaf(-sC, u2, S[4][c]);
                const float d1 = fmaf(var1, varf, 1e-5f);
                const float d2 = fmaf(var2, varf, 1e-5f);
                // cc1 + cc2 = (cross1^2*d2 + cross2^2*d1)/(d1*d2): single rcp
                const float inv = __builtin_amdgcn_rcpf(d1 * d2);
                float num = cross1 * cross1 * d2;
                num = fmaf(cross2 * cross2, d1, num);
                lsum += fmaf(-num, inv, 2.0f);   // (1-cc1)+(1-cc2)
            }
        }
    }

    // block reduction: wave shuffle -> LDS -> one atomic per block
#pragma unroll
    for (int offd = 32; offd > 0; offd >>= 1)
        lsum += __shfl_down(lsum, offd);
    __shared__ float wsum[4];
    const int lane = t & 63;
    const int wid  = t >> 6;
    if (lane == 0) wsum[wid] = lsum;
    __syncthreads();
    if (t == 0)
        atomicAdd(out, (wsum[0] + wsum[1] + wsum[2] + wsum[3]) * SCALE);
}

extern "C" void kernel_launch(void* const* d_in, const int* in_sizes, int n_in,
                              void* d_out, int out_size, void* d_ws, size_t ws_size,
                              hipStream_t stream) {
    const float* img1 = (const float*)d_in[0];
    const float* img2 = (const float*)d_in[1];
    const float* fimg = (const float*)d_in[2];
    float* out = (float*)d_out;

    hipMemsetAsync(out, 0, sizeof(float), stream);  // d_out re-poisoned each call

    dim3 grid(1, H / SEG, BATCH);        // (1, 32, 32) = 1024 blocks
    ncc_loss_kernel<<<grid, dim3(NT), 0, stream>>>(img1, img2, fimg, out);
}